// Round 1
// baseline (345.296 us; speedup 1.0000x reference)
//
#include <hip/hip_runtime.h>

#define INF_F 1e20f
#define B_ 16
#define Q_ 64
#define M_ 512
#define F_ 16
#define D_ 512

// K1: in_mem_base[b,m,d] = sum_f softmax(mask)[f] * in_memory[b,m,f,d]
//     out_mem[b,m,d]     = sum_f out_memory[b,m,f,d]
__global__ __launch_bounds__(128) void k_mem_reduce(
    const float* __restrict__ in_mem, const float* __restrict__ out_mem_in,
    const float* __restrict__ ctx_mask, float* __restrict__ in_mem_base,
    float* __restrict__ out_mem_sum)
{
    int bm = blockIdx.x;                 // b*M + m
    int t  = threadIdx.x;                // 0..127 -> float4 column
    const float* cm = ctx_mask + (size_t)bm * F_;
    float w[F_];
    float mx = -INF_F;
    #pragma unroll
    for (int f = 0; f < F_; ++f) {
        float c = cm[f];
        float v = c - (1.0f - c) * INF_F;
        w[f] = v; mx = fmaxf(mx, v);
    }
    float s = 0.f;
    #pragma unroll
    for (int f = 0; f < F_; ++f) { w[f] = __expf(w[f] - mx); s += w[f]; }
    float inv = 1.0f / s;
    const float4* ip = (const float4*)(in_mem     + (size_t)bm * F_ * D_);
    const float4* op = (const float4*)(out_mem_in + (size_t)bm * F_ * D_);
    float4 a = make_float4(0,0,0,0), o = make_float4(0,0,0,0);
    #pragma unroll
    for (int f = 0; f < F_; ++f) {
        float4 iv = ip[f*128 + t];
        float4 ov = op[f*128 + t];
        float wf = w[f] * inv;
        a.x += wf*iv.x; a.y += wf*iv.y; a.z += wf*iv.z; a.w += wf*iv.w;
        o.x += ov.x;    o.y += ov.y;    o.z += ov.z;    o.w += ov.w;
    }
    ((float4*)(in_mem_base + (size_t)bm * D_))[t] = a;
    ((float4*)(out_mem_sum + (size_t)bm * D_))[t] = o;
}

// K2: att_qm[b,q,m] = max_f( masked( query[b,q,:] . in_memory[b,m,f,:] ) )
// Block: 64 q x 256 rows (16 m x 16 f), 256 threads, 8x8 per-thread tile.
__global__ __launch_bounds__(256) void k_attention(
    const float* __restrict__ query, const float* __restrict__ in_mem,
    const float* __restrict__ ctx_mask, const float* __restrict__ query_mask,
    float* __restrict__ att_qm)
{
    __shared__ float4 As4[64 * 8];    // 8 KB,  [q][f4col^ (q&7)]
    __shared__ float4 Bs4[256 * 8];   // 32 KB, [r][f4col^ (r&7)]
    int b  = blockIdx.y;
    int t  = threadIdx.x;
    int ty = t >> 5;                  // 0..7  -> q group (8 q each)
    int tx = t & 31;                  // 0..31 -> r lane (r = j*32+tx)
    const float4* q4 = (const float4*)query;    // [B*Q][128]
    const float4* m4 = (const float4*)in_mem;   // [B*M*F][128]
    size_t qbase = (size_t)b * Q_ * 128;
    size_t mbase = (size_t)b * M_ * F_ * 128 + (size_t)blockIdx.x * 256 * 128;

    float acc[8][8];
    #pragma unroll
    for (int i = 0; i < 8; ++i)
        #pragma unroll
        for (int j = 0; j < 8; ++j) acc[i][j] = 0.f;

    for (int kc = 0; kc < 16; ++kc) {
        int k4 = kc * 8;
        #pragma unroll
        for (int i = 0; i < 2; ++i) {           // stage A: 512 float4
            int idx = t + i * 256;
            int row = idx >> 3, c = idx & 7;
            As4[row*8 + (c ^ (row & 7))] = q4[qbase + (size_t)row*128 + k4 + c];
        }
        #pragma unroll
        for (int i = 0; i < 8; ++i) {           // stage B: 2048 float4
            int idx = t + i * 256;
            int row = idx >> 3, c = idx & 7;
            Bs4[row*8 + (c ^ (row & 7))] = m4[mbase + (size_t)row*128 + k4 + c];
        }
        __syncthreads();
        #pragma unroll
        for (int d4 = 0; d4 < 8; ++d4) {
            float4 av[8], bv[8];
            #pragma unroll
            for (int i = 0; i < 8; ++i) av[i] = As4[(ty*8 + i)*8 + (d4 ^ i)];
            #pragma unroll
            for (int j = 0; j < 8; ++j) bv[j] = Bs4[(j*32 + tx)*8 + (d4 ^ (tx & 7))];
            #pragma unroll
            for (int i = 0; i < 8; ++i)
                #pragma unroll
                for (int j = 0; j < 8; ++j) {
                    acc[i][j] += av[i].x * bv[j].x;
                    acc[i][j] += av[i].y * bv[j].y;
                    acc[i][j] += av[i].z * bv[j].z;
                    acc[i][j] += av[i].w * bv[j].w;
                }
        }
        __syncthreads();
    }

    // masks + max over f (16-lane groups), write att_qm
    int m_base = blockIdx.x * 16;
    int f = tx & 15;
    #pragma unroll
    for (int j = 0; j < 8; ++j) {
        int m_loc = 2*j + (tx >> 4);
        float cmv = ctx_mask[((size_t)b*M_ + m_base + m_loc)*F_ + f];
        #pragma unroll
        for (int i = 0; i < 8; ++i) {
            int q = ty*8 + i;
            float qmv = query_mask[b*Q_ + q];
            float v = acc[i][j];
            v = cmv*v - (1.0f - cmv) * INF_F;
            v = qmv*v - (1.0f - qmv) * INF_F;
            #pragma unroll
            for (int s = 1; s < 16; s <<= 1) v = fmaxf(v, __shfl_xor(v, s, 64));
            if (f == 0)
                att_qm[((size_t)b*Q_ + q)*M_ + m_base + m_loc] = v;
        }
    }
}

// K3: probs[b,q,:] = softmax over M
__global__ __launch_bounds__(256) void k_softmax_m(
    const float* __restrict__ att, float* __restrict__ probs)
{
    int bq = blockIdx.x; int t = threadIdx.x;
    const float* row = att + (size_t)bq * M_;
    float v0 = row[t], v1 = row[t + 256];
    float mx = fmaxf(v0, v1);
    __shared__ float red[4];
    #pragma unroll
    for (int s = 1; s < 64; s <<= 1) mx = fmaxf(mx, __shfl_xor(mx, s, 64));
    if ((t & 63) == 0) red[t >> 6] = mx;
    __syncthreads();
    mx = fmaxf(fmaxf(red[0], red[1]), fmaxf(red[2], red[3]));
    float e0 = __expf(v0 - mx), e1 = __expf(v1 - mx);
    float sm = e0 + e1;
    __syncthreads();
    #pragma unroll
    for (int s = 1; s < 64; s <<= 1) sm += __shfl_xor(sm, s, 64);
    if ((t & 63) == 0) red[t >> 6] = sm;
    __syncthreads();
    sm = (red[0] + red[1]) + (red[2] + red[3]);
    float inv = 1.0f / sm;
    probs[(size_t)bq*M_ + t]       = e0 * inv;
    probs[(size_t)bq*M_ + t + 256] = e1 * inv;
}

// K3b: p2t[b,m,q] = softmax over Q of att_qm[b,:,m]  (stored transposed)
__global__ __launch_bounds__(256) void k_softmax_q(
    const float* __restrict__ att, float* __restrict__ p2t)
{
    __shared__ float T[64][65];
    __shared__ float cinv[64];
    int b = blockIdx.y, mc = blockIdx.x;   // mc: 0..7 (64-m tiles)
    int t = threadIdx.x;
    #pragma unroll
    for (int i = 0; i < 16; ++i) {
        int idx = t + i * 256;
        int q = idx >> 6, j = idx & 63;
        T[q][j] = att[((size_t)b*Q_ + q)*M_ + mc*64 + j];
    }
    __syncthreads();
    if (t < 64) {
        float mx = -INF_F;
        #pragma unroll
        for (int q = 0; q < 64; ++q) mx = fmaxf(mx, T[q][t]);
        float s = 0.f;
        #pragma unroll
        for (int q = 0; q < 64; ++q) { float e = __expf(T[q][t] - mx); T[q][t] = e; s += e; }
        cinv[t] = 1.0f / s;
    }
    __syncthreads();
    #pragma unroll
    for (int i = 0; i < 16; ++i) {
        int idx = t + i * 256;
        int j = idx >> 6, q = idx & 63;
        p2t[((size_t)b*M_ + mc*64 + j)*Q_ + q] = T[q][j] * cinv[j];
    }
}

// K5: new_query = query + probs @ out_mem
__global__ __launch_bounds__(128) void k_new_query(
    const float* __restrict__ query, const float* __restrict__ probs,
    const float* __restrict__ out_mem, float* __restrict__ new_q)
{
    __shared__ float P[8][512];    // 16 KB
    int b = blockIdx.y, q0 = blockIdx.x * 8;
    int t = threadIdx.x;           // 0..127 -> float4 d-column
    #pragma unroll
    for (int i = 0; i < 32; ++i) {
        int idx = t + i * 128;
        P[idx >> 9][idx & 511] = probs[((size_t)b*Q_ + q0 + (idx >> 9))*M_ + (idx & 511)];
    }
    __syncthreads();
    const float4* q4 = (const float4*)query;
    const float4* o4 = (const float4*)out_mem;
    float4 acc[8];
    #pragma unroll
    for (int qi = 0; qi < 8; ++qi) acc[qi] = q4[((size_t)b*Q_ + q0 + qi)*128 + t];
    for (int m = 0; m < M_; ++m) {
        float4 ov = o4[((size_t)b*M_ + m)*128 + t];
        #pragma unroll
        for (int qi = 0; qi < 8; ++qi) {
            float p = P[qi][m];
            acc[qi].x += p*ov.x; acc[qi].y += p*ov.y; acc[qi].z += p*ov.z; acc[qi].w += p*ov.w;
        }
    }
    float4* nq4 = (float4*)new_q;
    #pragma unroll
    for (int qi = 0; qi < 8; ++qi) nq4[((size_t)b*Q_ + q0 + qi)*128 + t] = acc[qi];
}

// K6: in_mem[b,m,:] += sum_q p2t[b,m,q] * new_query[b,q,:]
__global__ __launch_bounds__(128) void k_in_mem(
    const float* __restrict__ p2t, const float* __restrict__ new_q,
    float* __restrict__ in_mem_out)
{
    __shared__ float P[8][64];
    int b = blockIdx.y, m0 = blockIdx.x * 8;
    int t = threadIdx.x;
    #pragma unroll
    for (int i = 0; i < 4; ++i) {
        int idx = t + i * 128;
        P[idx >> 6][idx & 63] = p2t[((size_t)b*M_ + m0 + (idx >> 6))*Q_ + (idx & 63)];
    }
    __syncthreads();
    const float4* n4 = (const float4*)new_q;
    float4* im4 = (float4*)in_mem_out;
    float4 acc[8];
    #pragma unroll
    for (int mi = 0; mi < 8; ++mi) acc[mi] = im4[((size_t)b*M_ + m0 + mi)*128 + t];
    for (int q = 0; q < Q_; ++q) {
        float4 nv = n4[((size_t)b*Q_ + q)*128 + t];
        #pragma unroll
        for (int mi = 0; mi < 8; ++mi) {
            float p = P[mi][q];
            acc[mi].x += p*nv.x; acc[mi].y += p*nv.y; acc[mi].z += p*nv.z; acc[mi].w += p*nv.w;
        }
    }
    #pragma unroll
    for (int mi = 0; mi < 8; ++mi) im4[((size_t)b*M_ + m0 + mi)*128 + t] = acc[mi];
}

extern "C" void kernel_launch(void* const* d_in, const int* in_sizes, int n_in,
                              void* d_out, int out_size, void* d_ws, size_t ws_size,
                              hipStream_t stream)
{
    const float* query      = (const float*)d_in[0];
    const float* in_mem     = (const float*)d_in[1];
    const float* out_mem    = (const float*)d_in[2];
    const float* ctx_mask   = (const float*)d_in[3];
    const float* query_mask = (const float*)d_in[4];

    float* out = (float*)d_out;
    float* new_q      = out;                             // B*Q*D
    float* in_mem_out = out + (size_t)B_*Q_*D_;          // B*M*D
    float* out_mem_o  = in_mem_out + (size_t)B_*M_*D_;   // B*M*D

    float* ws     = (float*)d_ws;
    float* att_qm = ws;                                  // B*Q*M
    float* probs  = att_qm + (size_t)B_*Q_*M_;           // B*Q*M
    float* p2t    = probs  + (size_t)B_*Q_*M_;           // B*M*Q

    hipLaunchKernelGGL(k_mem_reduce, dim3(B_*M_), dim3(128), 0, stream,
                       in_mem, out_mem, ctx_mask, in_mem_out, out_mem_o);
    hipLaunchKernelGGL(k_attention, dim3(32, B_), dim3(256), 0, stream,
                       query, in_mem, ctx_mask, query_mask, att_qm);
    hipLaunchKernelGGL(k_softmax_m, dim3(B_*Q_), dim3(256), 0, stream, att_qm, probs);
    hipLaunchKernelGGL(k_softmax_q, dim3(8, B_), dim3(256), 0, stream, att_qm, p2t);
    hipLaunchKernelGGL(k_new_query, dim3(8, B_), dim3(128), 0, stream,
                       query, probs, out_mem_o, new_q);
    hipLaunchKernelGGL(k_in_mem, dim3(64, B_), dim3(128), 0, stream,
                       p2t, new_q, in_mem_out);
}